// Round 10
// baseline (274.613 us; speedup 1.0000x reference)
//
#include <hip/hip_runtime.h>

#define L2E 1.4426950408889634f

typedef _Float16 f16x8 __attribute__((ext_vector_type(8)));
typedef _Float16 f16x4 __attribute__((ext_vector_type(4)));
typedef float f32x4 __attribute__((ext_vector_type(4)));

__device__ __forceinline__ float sig_fast(float x) {
    return __builtin_amdgcn_rcpf(1.0f + __builtin_amdgcn_exp2f(-L2E * x));
}
__device__ __forceinline__ float tanh_fast(float x) {
    return 1.0f - 2.0f * __builtin_amdgcn_rcpf(1.0f + __builtin_amdgcn_exp2f(2.0f * L2E * x));
}
__device__ __forceinline__ float expnr_fast(float x) {  // exp(-relu(x))
    return __builtin_amdgcn_exp2f(-L2E * fmaxf(x, 0.0f));
}
// Orders LDS only; global loads/stores stay in flight across the barrier.
__device__ __forceinline__ void barrier_lds_only() {
    __asm__ volatile("s_waitcnt lgkmcnt(0)\n\ts_barrier" ::: "memory");
}

struct F8 { float v[8]; };
__device__ __forceinline__ F8 ld8(const float* p) {
    F8 r;
    float4 a = *(const float4*)p, b = *(const float4*)(p + 4);
    r.v[0]=a.x; r.v[1]=a.y; r.v[2]=a.z; r.v[3]=a.w;
    r.v[4]=b.x; r.v[5]=b.y; r.v[6]=b.z; r.v[7]=b.w;
    return r;
}
__device__ __forceinline__ f16x8 cvt8(F8 a) {
    f16x8 r;
#pragma unroll
    for (int q = 0; q < 8; ++q) r[q] = (_Float16)a.v[q];
    return r;
}
__device__ __forceinline__ f16x8 cvt8s(F8 a, F8 b) {
    f16x8 r;
#pragma unroll
    for (int q = 0; q < 8; ++q) r[q] = (_Float16)(a.v[q] + b.v[q]);
    return r;
}

// R10: 128 blocks x 8 batches = TWO independent 4-batch recurrence groups per
// block, interleaved in the same instruction stream (R5/R7/R9 all pinned at
// ~2400 cyc/step -> latency-bound serial chain; group B's independent work
// fills group A's MFMA/LDS/transcendental latency within one barrier period).
// 512 thr = 8 waves: waves 0-3 consumers (32 hidden cols each, both groups;
// weights SHARED across groups), waves 4-7 producers (x/m GEMM granule =
// 2 timesteps x 8 batches staged as 16 A-rows, one granule ahead, + tail
// projection + mu). Ring [slot][c][gate][b]: producer b64 writes, consumer
// u16 reads. No VGPR cap below natural footprint (R8 lesson).
__global__ __launch_bounds__(512, 2) void grud_kernel(
    const float* __restrict__ tp_pred, const float* __restrict__ X,
    const float* __restrict__ tp_true, const float* __restrict__ mask,
    const float* __restrict__ Wh_dec, const float* __restrict__ bh_dec,
    const float* __restrict__ Wx_dec, const float* __restrict__ bx_dec,
    const float* __restrict__ W_ih, const float* __restrict__ W_hh,
    const float* __restrict__ b_ih, const float* __restrict__ b_hh,
    const float* __restrict__ Wp, const float* __restrict__ bp,
    float* __restrict__ out)
{
    constexpr int VR = 136;            // V row stride (halfs)
    constexpr int AR = 136;            // Astage row stride
    constexpr int CS = 28;             // ring per-c stride: 3 gates x 8 b + 4 pad
    constexpr int RSLOT = 128 * CS;    // 3584 halfs per slot
    __shared__ alignas(16) _Float16 ring[4 * RSLOT];   // 28.7 KB
    __shared__ alignas(16) _Float16 V4[2][2][4 * VR];  // [group][buf][4 rows]
    __shared__ alignas(16) _Float16 Astage[2][16 * AR];
    __shared__ float dt_lds[120 * 8];                  // [t][b 0..7]
    __shared__ float mu_l[8][64];
    __shared__ float wxl[64], bxl[64];

    const int tid  = threadIdx.x;
    const int w    = tid >> 6, l = tid & 63, quad = l >> 4, lm = l & 15;
    const int b0   = blockIdx.x * 8;

    // zero V4 (t=0 state h=0), all groups/bufs: 2*2*4*VR halfs = 1088 uints
    for (int i = tid; i < 1088; i += 512) ((unsigned*)V4)[i] = 0;

    // dt: [t][b(8)]
    for (int i = tid; i < 960; i += 512) {
        int t = i >> 3, b = b0 + (i & 7);
        float v = 0.0f;
        if (t) {
            float cur = (t < 96) ? tp_true[b * 96 + t] : tp_pred[b * 24 + t - 96];
            float prv = (t - 1 < 96) ? tp_true[b * 96 + t - 1] : tp_pred[b * 24 + t - 97];
            v = cur - prv;
        }
        dt_lds[i] = v;
    }
    if (tid < 64) { wxl[tid] = Wx_dec[tid * 65]; bxl[tid] = bx_dec[tid]; }

    if (w >= 4) {
        // ===================== PRODUCER WAVES (4..7) =====================
        const int pw   = w - 4;          // 0..3
        const int ptid = tid - 256;      // 0..255
        const int c0   = 32 * pw + lm, c1 = c0 + 16;

        // mu: wave pw handles batches 2pw, 2pw+1 (lane l -> feature l)
        {
            const float* xr0 = X    + ((size_t)(b0 + 2 * pw) * 96) * 64 + l;
            const float* mr0 = mask + ((size_t)(b0 + 2 * pw) * 96) * 64 + l;
            const float* xr1 = X    + ((size_t)(b0 + 2 * pw + 1) * 96) * 64 + l;
            const float* mr1 = mask + ((size_t)(b0 + 2 * pw + 1) * 96) * 64 + l;
            float a0 = 0, cv0 = 0, a1 = 0, cv1 = 0;
#pragma unroll 4
            for (int t = 0; t < 96; ++t) {
                float x0 = xr0[t * 64], m0 = mr0[t * 64];
                float x1 = xr1[t * 64], m1 = mr1[t * 64];
                a0 += x0 * (1.0f - m0); cv0 += 1.0f - m0;
                a1 += x1 * (1.0f - m1); cv1 += 1.0f - m1;
            }
            mu_l[2 * pw][l]     = a0 / (cv0 + 24.0f);  // cnt >= 24, no clip
            mu_l[2 * pw + 1][l] = a1 / (cv1 + 24.0f);
        }

        // x/m-part B-frags: k<64 -> W_ih[:, :64]; k>=64 -> W_ih[:, 192:]
        f16x8 wxf[3][2][4];
#pragma unroll
        for (int g = 0; g < 3; ++g)
#pragma unroll
            for (int j = 0; j < 2; ++j)
#pragma unroll
                for (int fi = 0; fi < 4; ++fi) {
                    const int row = g * 128 + (j ? c1 : c0);
                    const int k0 = fi * 32 + quad * 8;
                    wxf[g][j][fi] = cvt8(ld8(W_ih + row * 256 + (k0 < 64 ? k0 : 128 + k0)));
                }

        // projection weights
        const int pn = pw * 16 + lm;
        const float bpv = bp[pn];
        f16x8 wPf[4];
#pragma unroll
        for (int fi = 0; fi < 4; ++fi)
            wPf[fi] = cvt8(ld8(Wp + pn * 128 + fi * 32 + quad * 8));

        // granule gp = timesteps {2gp, 2gp+1} x 8 batches; A-row R = 8*toff + b
        auto prodLoad = [&](int gp, float4& px, float4& pm) {
            if (gp >= 48) { px = make_float4(0,0,0,0); pm = make_float4(0,0,0,0); return; }
            const int R = ptid >> 4, toff = R >> 3, b = R & 7;
            const int tg = 2 * gp + toff;
            const size_t o = (((size_t)(b0 + b) * 96) + tg) * 64 + (ptid & 15) * 4;
            px = *(const float4*)(X + o);
            pm = *(const float4*)(mask + o);
        };
        auto prodStage = [&](int gp, float4 px, float4 pm) {
            const int R = ptid >> 4, toff = R >> 3, b = R & 7;
            const int tg = 2 * gp + toff, n0 = (ptid & 15) * 4;
            const float d = dt_lds[tg * 8 + b];
            const float xs[4] = {px.x, px.y, px.z, px.w};
            const float ms[4] = {pm.x, pm.y, pm.z, pm.w};
            f16x4 xi, mm;
#pragma unroll
            for (int e = 0; e < 4; ++e) {
                const int n = n0 + e;
                const float gxv = expnr_fast(d * wxl[n] + bxl[n]);
                const float muv = mu_l[b][n];
                float v;
                if (gp < 48) {  // LOCF collapse: m==0 -> X_locf == x_t
                    v = (ms[e] != 0.0f) ? xs[e] : (xs[e] - muv) * gxv + muv;
                    mm[e] = (_Float16)ms[e];
                } else {        // t>=96: x=0,m=0 -> x_in = (1-gx)*mu
                    v = (1.0f - gxv) * muv;
                    mm[e] = (_Float16)0.0f;
                }
                xi[e] = (_Float16)v;
            }
            *(f16x4*)&Astage[gp & 1][R * AR + n0]      = xi;
            *(f16x4*)&Astage[gp & 1][R * AR + 64 + n0] = mm;
        };
        auto prodMMA = [&](int gp) {
            f16x8 ap[4];
#pragma unroll
            for (int fi = 0; fi < 4; ++fi)
                ap[fi] = *(const f16x8*)&Astage[gp & 1][lm * AR + fi * 32 + quad * 8];
            f32x4 aR0 = {0,0,0,0}, aZ0 = {0,0,0,0}, aN0 = {0,0,0,0};
            f32x4 aR1 = {0,0,0,0}, aZ1 = {0,0,0,0}, aN1 = {0,0,0,0};
#pragma unroll
            for (int fi = 0; fi < 4; ++fi) {
                aR0 = __builtin_amdgcn_mfma_f32_16x16x32_f16(ap[fi], wxf[0][0][fi], aR0, 0, 0, 0);
                aZ0 = __builtin_amdgcn_mfma_f32_16x16x32_f16(ap[fi], wxf[1][0][fi], aZ0, 0, 0, 0);
                aN0 = __builtin_amdgcn_mfma_f32_16x16x32_f16(ap[fi], wxf[2][0][fi], aN0, 0, 0, 0);
                aR1 = __builtin_amdgcn_mfma_f32_16x16x32_f16(ap[fi], wxf[0][1][fi], aR1, 0, 0, 0);
                aZ1 = __builtin_amdgcn_mfma_f32_16x16x32_f16(ap[fi], wxf[1][1][fi], aZ1, 0, 0, 0);
                aN1 = __builtin_amdgcn_mfma_f32_16x16x32_f16(ap[fi], wxf[2][1][fi], aN1, 0, 0, 0);
            }
            // C/D row R = 4*quad+reg -> toff = quad>>1, b = (quad&1)*4 + reg
            const int toff = quad >> 1, bb = (quad & 1) * 4;
            const int slot = (2 * gp + toff) & 3;
            f16x4 pk;
            pk[0]=(_Float16)aR0[0]; pk[1]=(_Float16)aR0[1]; pk[2]=(_Float16)aR0[2]; pk[3]=(_Float16)aR0[3];
            *(f16x4*)&ring[slot * RSLOT + c0 * CS + 0 * 8 + bb] = pk;
            pk[0]=(_Float16)aZ0[0]; pk[1]=(_Float16)aZ0[1]; pk[2]=(_Float16)aZ0[2]; pk[3]=(_Float16)aZ0[3];
            *(f16x4*)&ring[slot * RSLOT + c0 * CS + 1 * 8 + bb] = pk;
            pk[0]=(_Float16)aN0[0]; pk[1]=(_Float16)aN0[1]; pk[2]=(_Float16)aN0[2]; pk[3]=(_Float16)aN0[3];
            *(f16x4*)&ring[slot * RSLOT + c0 * CS + 2 * 8 + bb] = pk;
            pk[0]=(_Float16)aR1[0]; pk[1]=(_Float16)aR1[1]; pk[2]=(_Float16)aR1[2]; pk[3]=(_Float16)aR1[3];
            *(f16x4*)&ring[slot * RSLOT + c1 * CS + 0 * 8 + bb] = pk;
            pk[0]=(_Float16)aZ1[0]; pk[1]=(_Float16)aZ1[1]; pk[2]=(_Float16)aZ1[2]; pk[3]=(_Float16)aZ1[3];
            *(f16x4*)&ring[slot * RSLOT + c1 * CS + 1 * 8 + bb] = pk;
            pk[0]=(_Float16)aN1[0]; pk[1]=(_Float16)aN1[1]; pk[2]=(_Float16)aN1[2]; pk[3]=(_Float16)aN1[3];
            *(f16x4*)&ring[slot * RSLOT + c1 * CS + 2 * 8 + bb] = pk;
        };

        float4 px[2], pm[2];
        __syncthreads();                 // #1: setup visible
        prodLoad(0, px[0], pm[0]);
        prodStage(0, px[0], pm[0]);
        barrier_lds_only();              // #2: Astage[0] staged before cross-wave read
        prodMMA(0);                      // ring slots 0,1
        prodLoad(1, px[1], pm[1]);
        barrier_lds_only();              // #3: granule 0 visible to consumers

        const int prow = (lm >> 2) * VR + quad * 8;
        for (int t = 0; t < 120; ++t) {
            const int k = t >> 1;
            if ((t & 1) == 0) {
                if (k + 2 < 60) prodLoad(k + 2, px[k & 1], pm[k & 1]);
                if (k + 1 < 60) prodStage(k + 1, px[(k + 1) & 1], pm[(k + 1) & 1]);
            } else {
                if (k + 1 < 60) prodMMA(k + 1);
            }

            if (t >= 96) {  // projection, both groups: rep_t = V4[g][t&1]
#pragma unroll
                for (int g = 0; g < 2; ++g) {
                    f16x8 af[4];
#pragma unroll
                    for (int fi = 0; fi < 4; ++fi)
                        af[fi] = *(const f16x8*)&V4[g][t & 1][prow + fi * 32];
                    f32x4 aP = {bpv, 0, 0, 0};
#pragma unroll
                    for (int fi = 0; fi < 4; ++fi)
                        aP = __builtin_amdgcn_mfma_f32_16x16x32_f16(af[fi], wPf[fi], aP, 0, 0, 0);
                    out[((size_t)(b0 + 4 * g + quad) * 24 + (t - 96)) * 64 + pn] = aP[0];
                }
            }
            barrier_lds_only();
        }
    } else {
        // ===================== CONSUMER WAVES (0..3) =====================
        const int c0 = 32 * w + lm, c1 = c0 + 16;

        // h-part B-frags (W_ih cols 64..191; +W_hh folded for r,z) — SHARED
        // across both groups: 32 frags = 128 VGPR.
        f16x8 wR[2][4], wZ[2][4], wN[2][4], wG[2][4];
        float S_[2], bh_[2], bR_[2], bZ_[2], bN_[2], bG_[2];
#pragma unroll
        for (int j = 0; j < 2; ++j) {
            const int c = j ? c1 : c0;
#pragma unroll
            for (int fi = 0; fi < 4; ++fi) {
                const int k0 = fi * 32 + quad * 8;
                wR[j][fi] = cvt8s(ld8(W_ih + c * 256 + 64 + k0),
                                  ld8(W_hh + c * 128 + k0));
                wZ[j][fi] = cvt8s(ld8(W_ih + (128 + c) * 256 + 64 + k0),
                                  ld8(W_hh + (128 + c) * 128 + k0));
                wN[j][fi] = cvt8(ld8(W_ih + (256 + c) * 256 + 64 + k0));
                wG[j][fi] = cvt8(ld8(W_hh + (256 + c) * 128 + k0));
            }
            float s = 0.0f;
            const float4* wh4 = (const float4*)(Wh_dec + c * 64);
#pragma unroll
            for (int i = 0; i < 16; ++i) { float4 u = wh4[i]; s += u.x + u.y + u.z + u.w; }
            S_[j]  = s;                       // dt @ Wh_dec.T = dt * rowsum
            bh_[j] = bh_dec[c];
            bR_[j] = b_ih[c] + b_hh[c];
            bZ_[j] = b_ih[128 + c] + b_hh[128 + c];
            bN_[j] = b_ih[256 + c];
            bG_[j] = b_hh[256 + c];
        }

        __syncthreads();      // #1
        barrier_lds_only();   // #2
        barrier_lds_only();   // #3

        const f32x4 ZV = {0.0f, 0.0f, 0.0f, 0.0f};
        const int vrow = (lm >> 2) * VR + quad * 8;
        float hA0 = 0, hA1 = 0, hB0 = 0, hB1 = 0;
        for (int t = 0; t < 120; ++t) {
            const _Float16* VpA = V4[0][t & 1];
            const _Float16* VpB = V4[1][t & 1];
            const int sb = (t & 3) * RSLOT;
            // Gx pre-sums: [c][gate][b], A: b=quad, B: b=quad+4
            float gA[2][3], gB[2][3];
#pragma unroll
            for (int j = 0; j < 2; ++j) {
                const int cb = (j ? c1 : c0) * CS;
#pragma unroll
                for (int g3 = 0; g3 < 3; ++g3) {
                    gA[j][g3] = (float)ring[sb + cb + g3 * 8 + quad];
                    gB[j][g3] = (float)ring[sb + cb + g3 * 8 + 4 + quad];
                }
            }
            f16x8 afA[4], afB[4];
#pragma unroll
            for (int fi = 0; fi < 4; ++fi) {
                afA[fi] = *(const f16x8*)&VpA[vrow + fi * 32];
                afB[fi] = *(const f16x8*)&VpB[vrow + fi * 32];
            }

            // gh(t+1), off the gate chain
            const int tn = (t < 119) ? t + 1 : 119;
            const float dnA = dt_lds[tn * 8 + quad];
            const float dnB = dt_lds[tn * 8 + 4 + quad];
            const float ghA0 = expnr_fast(dnA * S_[0] + bh_[0]);
            const float ghA1 = expnr_fast(dnA * S_[1] + bh_[1]);
            const float ghB0 = expnr_fast(dnB * S_[0] + bh_[0]);
            const float ghB1 = expnr_fast(dnB * S_[1] + bh_[1]);

            // ---- group A MFMAs (8 chains) ----
            f32x4 aR0 = __builtin_amdgcn_mfma_f32_16x16x32_f16(afA[0], wR[0][0], ZV, 0, 0, 0);
            f32x4 aZ0 = __builtin_amdgcn_mfma_f32_16x16x32_f16(afA[0], wZ[0][0], ZV, 0, 0, 0);
            f32x4 aN0 = __builtin_amdgcn_mfma_f32_16x16x32_f16(afA[0], wN[0][0], ZV, 0, 0, 0);
            f32x4 aG0 = __builtin_amdgcn_mfma_f32_16x16x32_f16(afA[0], wG[0][0], ZV, 0, 0, 0);
            f32x4 aR1 = __builtin_amdgcn_mfma_f32_16x16x32_f16(afA[0], wR[1][0], ZV, 0, 0, 0);
            f32x4 aZ1 = __builtin_amdgcn_mfma_f32_16x16x32_f16(afA[0], wZ[1][0], ZV, 0, 0, 0);
            f32x4 aN1 = __builtin_amdgcn_mfma_f32_16x16x32_f16(afA[0], wN[1][0], ZV, 0, 0, 0);
            f32x4 aG1 = __builtin_amdgcn_mfma_f32_16x16x32_f16(afA[0], wG[1][0], ZV, 0, 0, 0);
            // ---- group B MFMAs (8 chains) ----
            f32x4 bR0 = __builtin_amdgcn_mfma_f32_16x16x32_f16(afB[0], wR[0][0], ZV, 0, 0, 0);
            f32x4 bZ0 = __builtin_amdgcn_mfma_f32_16x16x32_f16(afB[0], wZ[0][0], ZV, 0, 0, 0);
            f32x4 bN0 = __builtin_amdgcn_mfma_f32_16x16x32_f16(afB[0], wN[0][0], ZV, 0, 0, 0);
            f32x4 bG0 = __builtin_amdgcn_mfma_f32_16x16x32_f16(afB[0], wG[0][0], ZV, 0, 0, 0);
            f32x4 bR1 = __builtin_amdgcn_mfma_f32_16x16x32_f16(afB[0], wR[1][0], ZV, 0, 0, 0);
            f32x4 bZ1 = __builtin_amdgcn_mfma_f32_16x16x32_f16(afB[0], wZ[1][0], ZV, 0, 0, 0);
            f32x4 bN1 = __builtin_amdgcn_mfma_f32_16x16x32_f16(afB[0], wN[1][0], ZV, 0, 0, 0);
            f32x4 bG1 = __builtin_amdgcn_mfma_f32_16x16x32_f16(afB[0], wG[1][0], ZV, 0, 0, 0);
#pragma unroll
            for (int fi = 1; fi < 4; ++fi) {
                aR0 = __builtin_amdgcn_mfma_f32_16x16x32_f16(afA[fi], wR[0][fi], aR0, 0, 0, 0);
                aZ0 = __builtin_amdgcn_mfma_f32_16x16x32_f16(afA[fi], wZ[0][fi], aZ0, 0, 0, 0);
                aN0 = __builtin_amdgcn_mfma_f32_16x16x32_f16(afA[fi], wN[0][fi], aN0, 0, 0, 0);
                aG0 = __builtin_amdgcn_mfma_f32_16x16x32_f16(afA[fi], wG[0][fi], aG0, 0, 0, 0);
                aR1 = __builtin_amdgcn_mfma_f32_16x16x32_f16(afA[fi], wR[1][fi], aR1, 0, 0, 0);
                aZ1 = __builtin_amdgcn_mfma_f32_16x16x32_f16(afA[fi], wZ[1][fi], aZ1, 0, 0, 0);
                aN1 = __builtin_amdgcn_mfma_f32_16x16x32_f16(afA[fi], wN[1][fi], aN1, 0, 0, 0);
                aG1 = __builtin_amdgcn_mfma_f32_16x16x32_f16(afA[fi], wG[1][fi], aG1, 0, 0, 0);
                bR0 = __builtin_amdgcn_mfma_f32_16x16x32_f16(afB[fi], wR[0][fi], bR0, 0, 0, 0);
                bZ0 = __builtin_amdgcn_mfma_f32_16x16x32_f16(afB[fi], wZ[0][fi], bZ0, 0, 0, 0);
                bN0 = __builtin_amdgcn_mfma_f32_16x16x32_f16(afB[fi], wN[0][fi], bN0, 0, 0, 0);
                bG0 = __builtin_amdgcn_mfma_f32_16x16x32_f16(afB[fi], wG[0][fi], bG0, 0, 0, 0);
                bR1 = __builtin_amdgcn_mfma_f32_16x16x32_f16(afB[fi], wR[1][fi], bR1, 0, 0, 0);
                bZ1 = __builtin_amdgcn_mfma_f32_16x16x32_f16(afB[fi], wZ[1][fi], bZ1, 0, 0, 0);
                bN1 = __builtin_amdgcn_mfma_f32_16x16x32_f16(afB[fi], wN[1][fi], bN1, 0, 0, 0);
                bG1 = __builtin_amdgcn_mfma_f32_16x16x32_f16(afB[fi], wG[1][fi], bG1, 0, 0, 0);
            }

            // gates (C/D reg 0: row 4*quad -> batch quad within group)
            {
                const float rg = sig_fast(aR0[0] + (gA[0][0] + bR_[0]));
                const float zg = sig_fast(aZ0[0] + (gA[0][1] + bZ_[0]));
                const float ng = tanh_fast(aN0[0] + (gA[0][2] + bN_[0]) + rg * (aG0[0] + bG_[0]));
                hA0 = (zg * (hA0 - ng) + ng) * ghA0;
            }
            {
                const float rg = sig_fast(aR1[0] + (gA[1][0] + bR_[1]));
                const float zg = sig_fast(aZ1[0] + (gA[1][1] + bZ_[1]));
                const float ng = tanh_fast(aN1[0] + (gA[1][2] + bN_[1]) + rg * (aG1[0] + bG_[1]));
                hA1 = (zg * (hA1 - ng) + ng) * ghA1;
            }
            {
                const float rg = sig_fast(bR0[0] + (gB[0][0] + bR_[0]));
                const float zg = sig_fast(bZ0[0] + (gB[0][1] + bZ_[0]));
                const float ng = tanh_fast(bN0[0] + (gB[0][2] + bN_[0]) + rg * (bG0[0] + bG_[0]));
                hB0 = (zg * (hB0 - ng) + ng) * ghB0;
            }
            {
                const float rg = sig_fast(bR1[0] + (gB[1][0] + bR_[1]));
                const float zg = sig_fast(bZ1[0] + (gB[1][1] + bZ_[1]));
                const float ng = tanh_fast(bN1[0] + (gB[1][2] + bN_[1]) + rg * (bG1[0] + bG_[1]));
                hB1 = (zg * (hB1 - ng) + ng) * ghB1;
            }
            if (t < 119) {
                _Float16* VnA = V4[0][(t & 1) ^ 1];
                _Float16* VnB = V4[1][(t & 1) ^ 1];
                VnA[quad * VR + c0] = (_Float16)hA0;
                VnA[quad * VR + c1] = (_Float16)hA1;
                VnB[quad * VR + c0] = (_Float16)hB0;
                VnB[quad * VR + c1] = (_Float16)hB1;
            }
            barrier_lds_only();
        }
    }
}

extern "C" void kernel_launch(void* const* d_in, const int* in_sizes, int n_in,
                              void* d_out, int out_size, void* d_ws, size_t ws_size,
                              hipStream_t stream) {
    const float* tp_pred = (const float*)d_in[0];
    const float* X       = (const float*)d_in[1];
    const float* tp_true = (const float*)d_in[2];
    const float* mask    = (const float*)d_in[3];
    const float* Wh_dec  = (const float*)d_in[4];
    const float* bh_dec  = (const float*)d_in[5];
    const float* Wx_dec  = (const float*)d_in[6];
    const float* bx_dec  = (const float*)d_in[7];
    const float* W_ih    = (const float*)d_in[8];
    const float* W_hh    = (const float*)d_in[9];
    const float* b_ih    = (const float*)d_in[10];
    const float* b_hh    = (const float*)d_in[11];
    const float* Wp      = (const float*)d_in[12];
    const float* bp      = (const float*)d_in[13];

    grud_kernel<<<dim3(128), dim3(512), 0, stream>>>(
        tp_pred, X, tp_true, mask, Wh_dec, bh_dec, Wx_dec, bx_dec,
        W_ih, W_hh, b_ih, b_hh, Wp, bp, (float*)d_out);
}